// Round 3
// baseline (196.513 us; speedup 1.0000x reference)
//
#include <hip/hip_runtime.h>
#include <math.h>

// ---------------- constants ----------------
#define NB 16384
#define DN 64
// output offsets (floats)
#define OFF1 491520      // data_LiDAR
#define OFF2 983040      // HSI_A
#define OFF3 1966080     // HSI_Dn
#define OFF4 1968000     // LiDAR_A
#define OFF5 2951040     // LiDAR_Dn
#define OFF6 2952960     // output
// ws offsets (floats)
#define SPH_OFF  0
#define SPL_OFF  1032192
#define DSPH_OFF 1048576
#define DSPL_OFF 1052608
#define DPTH_OFF 1052672
#define DPTL_OFF 1054592
#define D2H_OFF  1056512
#define D2L_OFF  1060352
#define AH_OFF   1064192
#define AL_OFF   2112768
#define PH_OFF   3161344
#define PL_OFF   3284224

__device__ __forceinline__ float wredmax(float v) {
#pragma unroll
    for (int m = 32; m; m >>= 1) v = fmaxf(v, __shfl_xor(v, m, 64));
    return v;
}
__device__ __forceinline__ float wredsum(float v) {
#pragma unroll
    for (int m = 32; m; m >>= 1) v += __shfl_xor(v, m, 64);
    return v;
}

// y[o] = scale*(bias[o] + sum_c W[o*RS+c]*x[c]) for o in [o0,o0+PER) ∩ [0,OUTS)
// k-outer / c-inner: weight row W[oc*RS ..] is CONTIGUOUS per k -> compiler
// emits s_load_dwordx8 streams (o0 is wave-uniform). PER independent fma
// chains give ILP; x preloaded once to registers.
template<int INS, int RS, int PER>
__device__ __forceinline__ void dlayer(const float* __restrict__ W,
                                       const float* __restrict__ bias,
                                       const float* __restrict__ xb,
                                       float* __restrict__ yb,
                                       const int OUTS, const int o0,
                                       const float scale)
{
    float x[INS];
#pragma unroll
    for (int c = 0; c < INS; ++c) x[c] = xb[c];
    float acc[PER];
#pragma unroll
    for (int k = 0; k < PER; ++k) {
        int oc = o0 + k; oc = oc < OUTS ? oc : OUTS - 1;
        float a = bias ? bias[oc] : 0.0f;
        const float* Wr = W + oc * RS;
#pragma unroll
        for (int c = 0; c < INS; ++c) a = fmaf(Wr[c], x[c], a);
        acc[k] = a;
    }
#pragma unroll
    for (int k = 0; k < PER; ++k) {
        int o = o0 + k;
        if (o < OUTS) yb[o] = acc[k] * scale;
    }
}

// y[o] = scale * sum_c W[c*CS+o]*x[c]  (transposed weights, no bias)
// c-outer / k-inner: W[c*CS+o0 .. +o0+PER) is contiguous per c.
template<int INS, int CS, int PER>
__device__ __forceinline__ void dlayerT(const float* __restrict__ W,
                                        const float* __restrict__ xb,
                                        float* __restrict__ yb,
                                        const int OUTS, const int o0,
                                        const float scale)
{
    float x[INS];
#pragma unroll
    for (int c = 0; c < INS; ++c) x[c] = xb[c];
    float acc[PER];
#pragma unroll
    for (int k = 0; k < PER; ++k) acc[k] = 0.0f;
#pragma unroll
    for (int c = 0; c < INS; ++c) {
        const float* Wr = W + c * CS + o0;
#pragma unroll
        for (int k = 0; k < PER; ++k) acc[k] = fmaf(Wr[k], x[c], acc[k]);
    }
#pragma unroll
    for (int k = 0; k < PER; ++k) {
        int o = o0 + k;
        if (o < OUTS) yb[o] = acc[k] * scale;
    }
}

// exp(S - max(S)) over a 64-wide row + per-wave partial sum. Running-max chain
// (no 64-reg array).
__device__ __forceinline__ void softmax_exp(const float* __restrict__ Sb,
                                            float* __restrict__ Qb,
                                            float* __restrict__ P,
                                            const int w, const int l)
{
    float mx = Sb[0];
#pragma unroll
    for (int j = 1; j < 64; ++j) mx = fmaxf(mx, Sb[j]);
    float ps = 0.f;
#pragma unroll
    for (int k = 0; k < 16; ++k) {
        float q = __expf(Sb[w * 16 + k] - mx);
        Qb[w * 16 + k] = q;
        ps += q;
    }
    P[w * 64 + l] = ps;
}

// ---------------- Kernel A: patch attention (4 items / block) ----------------
__global__ __launch_bounds__(256) void patch_attend_kernel(
    const float* __restrict__ patchH, const float* __restrict__ xH,
    const float* __restrict__ patchL, const float* __restrict__ xL,
    float* __restrict__ spH, float* __restrict__ spL)
{
    __shared__ float ph[4 * 3087];
    __shared__ float pl_[4 * 49];
    __shared__ float xh[4 * 63];
    __shared__ float xls[4];
    __shared__ float pw[4 * 49];

    const int tid = threadIdx.x;
    const int b0 = blockIdx.x * 4;
    {
        const float4* s4 = (const float4*)(patchH + (size_t)b0 * 3087);
        float4* d4 = (float4*)ph;
        for (int i = tid; i < 3087; i += 256) d4[i] = s4[i];
        if (tid < 49) ((float4*)pl_)[tid] = ((const float4*)(patchL + (size_t)b0 * 49))[tid];
        if (tid >= 64 && tid < 127) ((float4*)xh)[tid - 64] = ((const float4*)(xH + (size_t)b0 * 63))[tid - 64];
        if (tid == 255) *((float4*)xls) = *((const float4*)(xL + b0));
    }
    __syncthreads();

    const int w = tid >> 6, l = tid & 63;
    const float* phw = ph + w * 3087;
    const float* plw = pl_ + w * 49;
    const float* xhw = xh + w * 63;
    const float xlw = xls[w];

    float eh = -INFINITY, el = -INFINITY;
    if (l < 49) {
        float acc = 0.f;
#pragma unroll
        for (int c = 0; c < 63; ++c) {
            float t = xhw[c] - phw[c * 49 + l] + 1e-6f;
            acc = fmaf(t, t, acc);
        }
        eh = __expf(-sqrtf(acc));
        float tl = xlw - plw[l] + 1e-6f;
        el = __expf(-fabsf(tl));
    }
    float mh = wredmax(eh), ml = wredmax(el);
    float qh = (l < 49) ? __expf(eh - mh) : 0.f;
    float ql = (l < 49) ? __expf(el - ml) : 0.f;
    float sh = wredsum(qh);
    float sl = wredsum(ql);
    if (l < 49) pw[w * 49 + l] = qh / sh;
    float spl_v = wredsum((l < 49) ? plw[l] * (ql / sl) : 0.f);
    if (l == 0) spL[b0 + w] = spl_v;
    __syncthreads();
    if (l < 63) {
        float acc = 0.f;
        const float* pww = pw + w * 49;
#pragma unroll
        for (int s = 0; s < 49; ++s) acc = fmaf(phw[l * 49 + s], pww[s], acc);
        spH[(size_t)(b0 + w) * 63 + l] = acc;
    }
}

// ---------------- Kernel C: dictionary chain (1 block, lane = atom) ----------------
__global__ __launch_bounds__(256) void dict_chain_kernel(
    const float* __restrict__ dsph, const float* __restrict__ dspl,
    const float* __restrict__ w1_1, const float* __restrict__ b1_1,
    const float* __restrict__ w1_2, const float* __restrict__ b1_2,
    const float* __restrict__ w2_1, const float* __restrict__ b2_1,
    const float* __restrict__ w2_2, const float* __restrict__ b2_2,
    const float* __restrict__ wa2, const float* __restrict__ ba2,
    float* __restrict__ dptH, float* __restrict__ dptL,
    float* __restrict__ d2H, float* __restrict__ d2L)
{
    __shared__ float B0[64 * 65];
    __shared__ float B1[64 * 65];
    __shared__ float XLs[64];
    const int tid = threadIdx.x;
    const int w = __builtin_amdgcn_readfirstlane(tid >> 6);
    const int l = tid & 63;
    {
        const float4* s4 = (const float4*)dsph;
        float4* d4 = (float4*)B0;
        for (int i = tid; i < 1008; i += 256) d4[i] = s4[i];
        if (tid < 16) ((float4*)XLs)[tid] = ((const float4*)dspl)[tid];
    }
    __syncthreads();
    dlayer<63, 63, 12>(w1_1, b1_1, B0 + l * 63, B1 + l * 45, 45, w * 12, 1.0f);
    __syncthreads();
    dlayer<45, 45, 8>(w1_2, b1_2, B1 + l * 45, B0 + l * 30, 30, w * 8, 1.0f);
    __syncthreads();
    for (int i = tid; i < 1920; i += 256) dptH[i] = B0[i];
    dlayer<30, 30, 15>(wa2, ba2, B0 + l * 30, B1 + l * 61, 60, w * 15, 1.0f);
    __syncthreads();
    for (int i = tid; i < 3840; i += 256) { int r = i / 60, c = i - r * 60; d2H[i] = B1[r * 61 + c]; }
    dlayer<1, 1, 4>(w2_1, b2_1, XLs + l, B0 + l * 15, 15, w * 4, 1.0f);
    __syncthreads();
    dlayer<15, 15, 8>(w2_2, b2_2, B0 + l * 15, B1 + l * 30, 30, w * 8, 1.0f);
    __syncthreads();
    for (int i = tid; i < 1920; i += 256) dptL[i] = B1[i];
    dlayer<30, 30, 15>(wa2, ba2, B1 + l * 30, B0 + l * 61, 60, w * 15, 1.0f);
    __syncthreads();
    for (int i = tid; i < 3840; i += 256) { int r = i / 60, c = i - r * 60; d2L[i] = B0[r * 61 + c]; }
}

// ---------------- Kernel B: per-item chain, HSI & LiDAR interleaved ----------------
__global__ __launch_bounds__(256) void chain_kernel(
    const float* __restrict__ spH, const float* __restrict__ spL,
    const float* __restrict__ dptH, const float* __restrict__ dptL,
    const float* __restrict__ d2H, const float* __restrict__ d2L,
    const float* __restrict__ w1_1, const float* __restrict__ b1_1,
    const float* __restrict__ w1_2, const float* __restrict__ b1_2,
    const float* __restrict__ w2_1, const float* __restrict__ b2_1,
    const float* __restrict__ w2_2, const float* __restrict__ b2_2,
    const float* __restrict__ wa1, const float* __restrict__ ba1,
    const float* __restrict__ wo1, const float* __restrict__ bo1,
    const float* __restrict__ wo2, const float* __restrict__ bo2,
    const int* __restrict__ mI,
    float* __restrict__ out, float* __restrict__ aH, float* __restrict__ aL)
{
    __shared__ float HA[64 * 65];
    __shared__ float HB[64 * 65];
    __shared__ float LA[64 * 65];
    __shared__ float LB[64 * 65];
    __shared__ float XLs[64];
    __shared__ float PH[256], PL[256];

    const int tid = threadIdx.x;
    const int w = __builtin_amdgcn_readfirstlane(tid >> 6);
    const int l = tid & 63;
    const int b0 = blockIdx.x * 64;
    const int b = b0 + l;
    const float mf = (float)(*mI);

    for (int i = tid; i < 4032; i += 256) {
        int r = i / 63, c = i - r * 63;
        HA[r * 65 + c] = spH[(size_t)b0 * 63 + i];
    }
    if (tid < 64) XLs[tid] = spL[b0 + tid];
    __syncthreads();

    // s1: H 63->45 ; L 1->15
    dlayer<63, 63, 12>(w1_1, b1_1, HA + l * 65, HB + l * 65, 45, w * 12, 1.0f);
    __builtin_amdgcn_sched_barrier(0);
    dlayer<1, 1, 4>(w2_1, b2_1, XLs + l, LA + l * 65, 15, w * 4, 1.0f);
    __syncthreads();
    // s2: H 45->30 ; L 15->30
    dlayer<45, 45, 8>(w1_2, b1_2, HB + l * 65, HA + l * 65, 30, w * 8, 1.0f);
    __builtin_amdgcn_sched_barrier(0);
    dlayer<15, 15, 8>(w2_2, b2_2, LA + l * 65, LB + l * 65, 30, w * 8, 1.0f);
    __syncthreads();
    // data_HSI / data_LiDAR copies + s3: 30->60 (wa1) both branches
    for (int i = tid; i < 1920; i += 256) {
        int r = i / 30, c = i - r * 30;
        out[(size_t)b0 * 30 + i] = HA[r * 65 + c];
        out[OFF1 + (size_t)b0 * 30 + i] = LB[r * 65 + c];
    }
    dlayer<30, 30, 15>(wa1, ba1, HA + l * 65, HB + l * 65, 60, w * 15, 1.0f);
    __builtin_amdgcn_sched_barrier(0);
    dlayer<30, 30, 15>(wa1, ba1, LB + l * 65, LA + l * 65, 60, w * 15, 1.0f);
    __syncthreads();
    // s4: S = H1 @ D2^T  (60->64) both branches
    dlayer<60, 60, 16>(d2H, nullptr, HB + l * 65, HA + l * 65, 64, w * 16, 1.0f);
    __builtin_amdgcn_sched_barrier(0);
    dlayer<60, 60, 16>(d2L, nullptr, LA + l * 65, LB + l * 65, 64, w * 16, 1.0f);
    __syncthreads();
    // s5: exp(S - max) both branches
    softmax_exp(HA + l * 65, HB + l * 65, PH, w, l);
    __builtin_amdgcn_sched_barrier(0);
    softmax_exp(LB + l * 65, LA + l * 65, PL, w, l);
    __syncthreads();
    // A-matrix writes (only consumed when m != 1)
    if (mf != 1.0f) {
        for (int i = tid; i < 4096; i += 256) {
            int r = i >> 6, j = i & 63;
            float ih = 1.0f / (PH[r] + PH[64 + r] + PH[128 + r] + PH[192 + r]);
            float il = 1.0f / (PL[r] + PL[64 + r] + PL[128 + r] + PL[192 + r]);
            aH[(size_t)b0 * 64 + i] = HB[r * 65 + j] * ih;
            aL[(size_t)b0 * 64 + i] = LA[r * 65 + j] * il;
        }
    }
    {
        const float invH = 1.0f / (PH[l] + PH[64 + l] + PH[128 + l] + PH[192 + l]);
        const float invL = 1.0f / (PL[l] + PL[64 + l] + PL[128 + l] + PL[192 + l]);
        dlayerT<64, 30, 8>(dptH, HB + l * 65, HA + l * 65, 30, w * 8, invH);
        __builtin_amdgcn_sched_barrier(0);
        dlayerT<64, 30, 8>(dptL, LA + l * 65, LB + l * 65, 30, w * 8, invL);
    }
    __syncthreads();
    // s8: 30->60 (wa1) both branches
    dlayer<30, 30, 15>(wa1, ba1, HA + l * 65, HB + l * 65, 60, w * 15, 1.0f);
    __builtin_amdgcn_sched_barrier(0);
    dlayer<30, 30, 15>(wa1, ba1, LB + l * 65, LA + l * 65, 60, w * 15, 1.0f);
    __syncthreads();
    // HSI_A / LiDAR_A copies
    for (int i = tid; i < 3840; i += 256) {
        int r = i / 60, c = i - r * 60;
        out[OFF2 + (size_t)b0 * 60 + i] = HB[r * 65 + c];
        out[OFF4 + (size_t)b0 * 60 + i] = LA[r * 65 + c];
    }
    // o1: 120->60, split into two 60-wide halves to cap register pressure
    {
        const int o0 = w * 15;
        float acc[15];
#pragma unroll
        for (int k = 0; k < 15; ++k) acc[k] = bo1[o0 + k];
        {
            float x[60];
#pragma unroll
            for (int c = 0; c < 60; ++c) x[c] = LA[l * 65 + c];
#pragma unroll
            for (int k = 0; k < 15; ++k) {
                const float* Wr = wo1 + (o0 + k) * 120;
                float a = acc[k];
#pragma unroll
                for (int c = 0; c < 60; ++c) a = fmaf(Wr[c], x[c], a);
                acc[k] = a;
            }
        }
        __builtin_amdgcn_sched_barrier(0);
        {
            float x[60];
#pragma unroll
            for (int c = 0; c < 60; ++c) x[c] = HB[l * 65 + c];
#pragma unroll
            for (int k = 0; k < 15; ++k) {
                const float* Wr = wo1 + (o0 + k) * 120 + 60;
                float a = acc[k];
#pragma unroll
                for (int c = 0; c < 60; ++c) a = fmaf(Wr[c], x[c], a);
                acc[k] = a;
            }
        }
#pragma unroll
        for (int k = 0; k < 15; ++k) HA[l * 65 + o0 + k] = acc[k];
    }
    __syncthreads();
    // o2: 60->7
    {
        float x[60];
#pragma unroll
        for (int c = 0; c < 60; ++c) x[c] = HA[l * 65 + c];
#pragma unroll
        for (int k = 0; k < 2; ++k) {
            int o = w * 2 + k;
            if (o < 7) {
                float a = bo2[o];
                const float* Wr = wo2 + o * 60;
#pragma unroll
                for (int c = 0; c < 60; ++c) a = fmaf(Wr[c], x[c], a);
                out[OFF6 + (size_t)b * 7 + o] = a;
            }
        }
    }
}

// ---------------- Kernel D1: momentum partial (only real work when m != 1) ----------------
__global__ __launch_bounds__(256) void momentum_partial_kernel(
    const float* __restrict__ dataH, const float* __restrict__ dataL,
    const float* __restrict__ aH, const float* __restrict__ aL,
    float* __restrict__ pH, float* __restrict__ pL,
    const int* __restrict__ mI)
{
    const float mf = (float)(*mI);
    if (mf == 1.0f) return;  // P is never read when m == 1
    const int tid = threadIdx.x;
    const int chunk = blockIdx.x & 63;
    const int mod = blockIdx.x >> 6;
    const float* data = mod ? dataL : dataH;
    const float* A = mod ? aL : aH;
    float* P = mod ? pL : pH;
    const int b0 = chunk * 256;
    const int j = tid & 63;
    const int g = tid >> 6;
    float acc[8];
#pragma unroll
    for (int k = 0; k < 8; ++k) acc[k] = 0.f;
    for (int bb = 0; bb < 256; ++bb) {
        float a = A[(size_t)(b0 + bb) * 64 + j];
#pragma unroll
        for (int k = 0; k < 8; ++k) {
            int c = g + 4 * k; c = c < 30 ? c : 29;
            acc[k] = fmaf(data[(size_t)(b0 + bb) * 30 + c], a, acc[k]);
        }
    }
#pragma unroll
    for (int k = 0; k < 8; ++k) {
        int c = g + 4 * k;
        if (c < 30) P[chunk * 1920 + c * 64 + j] = acc[k];
    }
}

// ---------------- Kernel D2: Dn = m*Dp + (1-m)*sum(partials) ----------------
__global__ __launch_bounds__(256) void momentum_final_kernel(
    const float* __restrict__ dptH, const float* __restrict__ dptL,
    const float* __restrict__ pH, const float* __restrict__ pL,
    const int* __restrict__ mI, float* __restrict__ out)
{
    int t = blockIdx.x * 256 + threadIdx.x;
    if (t >= 3840) return;
    const int mod = t >= 1920;
    const int idx = mod ? t - 1920 : t;
    const int c = idx >> 6, j = idx & 63;
    const float mf = (float)(*mI);
    const float* dpt = mod ? dptL : dptH;
    float v = mf * dpt[j * 30 + c];
    if (mf != 1.0f) {
        const float* P = mod ? pL : pH;
        float s = 0.f;
        for (int k = 0; k < 64; ++k) s += P[k * 1920 + idx];
        v += (1.0f - mf) * s;
    }
    out[(mod ? OFF5 : OFF3) + idx] = v;
}

extern "C" void kernel_launch(void* const* d_in, const int* in_sizes, int n_in,
                              void* d_out, int out_size, void* d_ws, size_t ws_size,
                              hipStream_t stream) {
    const float* H_HSI        = (const float*)d_in[0];
    const float* H_LiDAR      = (const float*)d_in[1];
    const float* HSI_D        = (const float*)d_in[2];
    const float* LiDAR_D      = (const float*)d_in[3];
    const float* Patch_HSI    = (const float*)d_in[4];
    const float* Patch_LiDAR  = (const float*)d_in[5];
    const float* D_Patch_HSI  = (const float*)d_in[6];
    const float* D_Patch_LiDAR= (const float*)d_in[7];
    const int*   mI           = (const int*)d_in[9];
    const float* w1_1 = (const float*)d_in[12];
    const float* b1_1 = (const float*)d_in[13];
    const float* w1_2 = (const float*)d_in[14];
    const float* b1_2 = (const float*)d_in[15];
    const float* w2_1 = (const float*)d_in[16];
    const float* b2_1 = (const float*)d_in[17];
    const float* w2_2 = (const float*)d_in[18];
    const float* b2_2 = (const float*)d_in[19];
    const float* wa1  = (const float*)d_in[20];
    const float* ba1  = (const float*)d_in[21];
    const float* wa2  = (const float*)d_in[22];
    const float* ba2  = (const float*)d_in[23];
    const float* wo1  = (const float*)d_in[24];
    const float* bo1  = (const float*)d_in[25];
    const float* wo2  = (const float*)d_in[26];
    const float* bo2  = (const float*)d_in[27];

    float* out = (float*)d_out;
    float* ws  = (float*)d_ws;

    patch_attend_kernel<<<NB / 4, 256, 0, stream>>>(
        Patch_HSI, H_HSI, Patch_LiDAR, H_LiDAR, ws + SPH_OFF, ws + SPL_OFF);
    patch_attend_kernel<<<DN / 4, 256, 0, stream>>>(
        D_Patch_HSI, HSI_D, D_Patch_LiDAR, LiDAR_D, ws + DSPH_OFF, ws + DSPL_OFF);
    dict_chain_kernel<<<1, 256, 0, stream>>>(
        ws + DSPH_OFF, ws + DSPL_OFF,
        w1_1, b1_1, w1_2, b1_2, w2_1, b2_1, w2_2, b2_2, wa2, ba2,
        ws + DPTH_OFF, ws + DPTL_OFF, ws + D2H_OFF, ws + D2L_OFF);
    chain_kernel<<<NB / 64, 256, 0, stream>>>(
        ws + SPH_OFF, ws + SPL_OFF,
        ws + DPTH_OFF, ws + DPTL_OFF, ws + D2H_OFF, ws + D2L_OFF,
        w1_1, b1_1, w1_2, b1_2, w2_1, b2_1, w2_2, b2_2,
        wa1, ba1, wo1, bo1, wo2, bo2, mI,
        out, ws + AH_OFF, ws + AL_OFF);
    momentum_partial_kernel<<<128, 256, 0, stream>>>(
        out, out + OFF1, ws + AH_OFF, ws + AL_OFF, ws + PH_OFF, ws + PL_OFF, mI);
    momentum_final_kernel<<<15, 256, 0, stream>>>(
        ws + DPTH_OFF, ws + DPTL_OFF, ws + PH_OFF, ws + PL_OFF, mI, out);
}

// Round 4
// 114.846 us; speedup vs baseline: 1.7111x; 1.7111x over previous
//
#include <hip/hip_runtime.h>
#include <math.h>

// ---------------- constants ----------------
#define NB 16384
#define DN 64
// output offsets (floats)
#define OFF1 491520      // data_LiDAR
#define OFF2 983040      // HSI_A
#define OFF3 1966080     // HSI_Dn
#define OFF4 1968000     // LiDAR_A
#define OFF5 2951040     // LiDAR_Dn
#define OFF6 2952960     // output
// ws offsets (floats)
#define SPH_OFF  0
#define SPL_OFF  1032192
#define DSPH_OFF 1048576
#define DSPL_OFF 1052608
#define DPTH_OFF 1052672
#define DPTL_OFF 1054592
#define D2H_OFF  1056512
#define D2L_OFF  1060352
#define AH_OFF   1064192
#define AL_OFF   2112768
#define PH_OFF   3161344
#define PL_OFF   3284224

__device__ __forceinline__ float wredmax(float v) {
#pragma unroll
    for (int m = 32; m; m >>= 1) v = fmaxf(v, __shfl_xor(v, m, 64));
    return v;
}
__device__ __forceinline__ float wredsum(float v) {
#pragma unroll
    for (int m = 32; m; m >>= 1) v += __shfl_xor(v, m, 64);
    return v;
}

// y[o] = scale*(bias[o] + sum_c W[o*RS+c]*x[c]) for o in [o0,o0+PER) ∩ [0,OUTS)
// k-outer weight rows (contiguous -> s_load streams, o0 wave-uniform);
// x read from LDS in chunks of 16 to cap register pressure (16 waves/CU
// needs VGPR <= 128).
template<int INS, int RS, int PER>
__device__ __forceinline__ void dlayer(const float* __restrict__ W,
                                       const float* __restrict__ bias,
                                       const float* __restrict__ xb,
                                       float* __restrict__ yb,
                                       const int OUTS, const int o0,
                                       const float scale)
{
    float acc[PER];
#pragma unroll
    for (int k = 0; k < PER; ++k) {
        int oc = o0 + k; oc = oc < OUTS ? oc : OUTS - 1;
        acc[k] = bias ? bias[oc] : 0.0f;
    }
#pragma unroll
    for (int c0 = 0; c0 < INS; c0 += 16) {
        const int CH = (INS - c0) < 16 ? (INS - c0) : 16;
        float x[16];
#pragma unroll
        for (int j = 0; j < CH; ++j) x[j] = xb[c0 + j];
#pragma unroll
        for (int k = 0; k < PER; ++k) {
            int oc = o0 + k; oc = oc < OUTS ? oc : OUTS - 1;
            const float* Wr = W + oc * RS + c0;
            float a = acc[k];
#pragma unroll
            for (int j = 0; j < CH; ++j) a = fmaf(Wr[j], x[j], a);
            acc[k] = a;
        }
    }
#pragma unroll
    for (int k = 0; k < PER; ++k) {
        int o = o0 + k;
        if (o < OUTS) yb[o] = acc[k] * scale;
    }
}

// y[o] = scale * sum_c W[c*CS+o]*x[c]  (transposed weights, no bias)
template<int INS, int CS, int PER>
__device__ __forceinline__ void dlayerT(const float* __restrict__ W,
                                        const float* __restrict__ xb,
                                        float* __restrict__ yb,
                                        const int OUTS, const int o0,
                                        const float scale)
{
    float acc[PER];
#pragma unroll
    for (int k = 0; k < PER; ++k) acc[k] = 0.0f;
#pragma unroll
    for (int c0 = 0; c0 < INS; c0 += 16) {
        const int CH = (INS - c0) < 16 ? (INS - c0) : 16;
        float x[16];
#pragma unroll
        for (int j = 0; j < CH; ++j) x[j] = xb[c0 + j];
#pragma unroll
        for (int j = 0; j < CH; ++j) {
            const float* Wr = W + (c0 + j) * CS + o0;
#pragma unroll
            for (int k = 0; k < PER; ++k) acc[k] = fmaf(Wr[k], x[j], acc[k]);
        }
    }
#pragma unroll
    for (int k = 0; k < PER; ++k) {
        int o = o0 + k;
        if (o < OUTS) yb[o] = acc[k] * scale;
    }
}

// exp(S - max(S)) over a 64-wide row; each of 16 waves covers 4 cols.
__device__ __forceinline__ void softmax_exp4(const float* __restrict__ Sb,
                                             float* __restrict__ Qb,
                                             float* __restrict__ P,
                                             const int w, const int l)
{
    float m0 = Sb[0], m1 = Sb[1], m2 = Sb[2], m3 = Sb[3];
#pragma unroll
    for (int j = 4; j < 64; j += 4) {
        m0 = fmaxf(m0, Sb[j]);
        m1 = fmaxf(m1, Sb[j + 1]);
        m2 = fmaxf(m2, Sb[j + 2]);
        m3 = fmaxf(m3, Sb[j + 3]);
    }
    const float mx = fmaxf(fmaxf(m0, m1), fmaxf(m2, m3));
    float ps = 0.f;
#pragma unroll
    for (int k = 0; k < 4; ++k) {
        float q = __expf(Sb[w * 4 + k] - mx);
        Qb[w * 4 + k] = q;
        ps += q;
    }
    P[w * 64 + l] = ps;
}

// 1/sum over 16 per-wave partials
__device__ __forceinline__ float inv16(const float* __restrict__ P, const int l)
{
    float s0 = P[l], s1 = P[64 + l], s2 = P[128 + l], s3 = P[192 + l];
#pragma unroll
    for (int g = 4; g < 16; g += 4) {
        s0 += P[g * 64 + l];
        s1 += P[(g + 1) * 64 + l];
        s2 += P[(g + 2) * 64 + l];
        s3 += P[(g + 3) * 64 + l];
    }
    return 1.0f / ((s0 + s1) + (s2 + s3));
}

// ---------------- Kernel A: patch attention (4 items / block) ----------------
__global__ __launch_bounds__(256) void patch_attend_kernel(
    const float* __restrict__ patchH, const float* __restrict__ xH,
    const float* __restrict__ patchL, const float* __restrict__ xL,
    float* __restrict__ spH, float* __restrict__ spL)
{
    __shared__ float ph[4 * 3087];
    __shared__ float pl_[4 * 49];
    __shared__ float xh[4 * 63];
    __shared__ float xls[4];
    __shared__ float pw[4 * 49];

    const int tid = threadIdx.x;
    const int b0 = blockIdx.x * 4;
    {
        const float4* s4 = (const float4*)(patchH + (size_t)b0 * 3087);
        float4* d4 = (float4*)ph;
        for (int i = tid; i < 3087; i += 256) d4[i] = s4[i];
        if (tid < 49) ((float4*)pl_)[tid] = ((const float4*)(patchL + (size_t)b0 * 49))[tid];
        if (tid >= 64 && tid < 127) ((float4*)xh)[tid - 64] = ((const float4*)(xH + (size_t)b0 * 63))[tid - 64];
        if (tid == 255) *((float4*)xls) = *((const float4*)(xL + b0));
    }
    __syncthreads();

    const int w = tid >> 6, l = tid & 63;
    const float* phw = ph + w * 3087;
    const float* plw = pl_ + w * 49;
    const float* xhw = xh + w * 63;
    const float xlw = xls[w];

    float eh = -INFINITY, el = -INFINITY;
    if (l < 49) {
        float acc = 0.f;
#pragma unroll
        for (int c = 0; c < 63; ++c) {
            float t = xhw[c] - phw[c * 49 + l] + 1e-6f;
            acc = fmaf(t, t, acc);
        }
        eh = __expf(-sqrtf(acc));
        float tl = xlw - plw[l] + 1e-6f;
        el = __expf(-fabsf(tl));
    }
    float mh = wredmax(eh), ml = wredmax(el);
    float qh = (l < 49) ? __expf(eh - mh) : 0.f;
    float ql = (l < 49) ? __expf(el - ml) : 0.f;
    float sh = wredsum(qh);
    float sl = wredsum(ql);
    if (l < 49) pw[w * 49 + l] = qh / sh;
    float spl_v = wredsum((l < 49) ? plw[l] * (ql / sl) : 0.f);
    if (l == 0) spL[b0 + w] = spl_v;
    __syncthreads();
    if (l < 63) {
        float acc = 0.f;
        const float* pww = pw + w * 49;
#pragma unroll
        for (int s = 0; s < 49; ++s) acc = fmaf(phw[l * 49 + s], pww[s], acc);
        spH[(size_t)(b0 + w) * 63 + l] = acc;
    }
}

// ---------------- Kernel C: dictionary chain (1 block, 16 waves, lane = atom) ----------------
__global__ __launch_bounds__(1024) void dict_chain_kernel(
    const float* __restrict__ dsph, const float* __restrict__ dspl,
    const float* __restrict__ w1_1, const float* __restrict__ b1_1,
    const float* __restrict__ w1_2, const float* __restrict__ b1_2,
    const float* __restrict__ w2_1, const float* __restrict__ b2_1,
    const float* __restrict__ w2_2, const float* __restrict__ b2_2,
    const float* __restrict__ wa2, const float* __restrict__ ba2,
    float* __restrict__ dptH, float* __restrict__ dptL,
    float* __restrict__ d2H, float* __restrict__ d2L)
{
    __shared__ float B0[64 * 65];
    __shared__ float B1[64 * 65];
    __shared__ float XLs[64];
    const int tid = threadIdx.x;
    const int w = __builtin_amdgcn_readfirstlane(tid >> 6);
    const int l = tid & 63;
    {
        const float4* s4 = (const float4*)dsph;
        float4* d4 = (float4*)B0;
        if (tid < 1008) d4[tid] = s4[tid];
        else if (tid >= 1008 && tid < 1024 && (tid - 1008) < 16)
            ((float4*)XLs)[tid - 1008] = ((const float4*)dspl)[tid - 1008];
    }
    __syncthreads();
    dlayer<63, 63, 3>(w1_1, b1_1, B0 + l * 63, B1 + l * 45, 45, w * 3, 1.0f);
    __syncthreads();
    dlayer<45, 45, 2>(w1_2, b1_2, B1 + l * 45, B0 + l * 30, 30, w * 2, 1.0f);
    __syncthreads();
    for (int i = tid; i < 1920; i += 1024) dptH[i] = B0[i];
    dlayer<30, 30, 4>(wa2, ba2, B0 + l * 30, B1 + l * 61, 60, w * 4, 1.0f);
    __syncthreads();
    for (int i = tid; i < 3840; i += 1024) { int r = i / 60, c = i - r * 60; d2H[i] = B1[r * 61 + c]; }
    dlayer<1, 1, 1>(w2_1, b2_1, XLs + l, B0 + l * 15, 15, w, 1.0f);
    __syncthreads();
    dlayer<15, 15, 2>(w2_2, b2_2, B0 + l * 15, B1 + l * 30, 30, w * 2, 1.0f);
    __syncthreads();
    for (int i = tid; i < 1920; i += 1024) dptL[i] = B1[i];
    dlayer<30, 30, 4>(wa2, ba2, B1 + l * 30, B0 + l * 61, 60, w * 4, 1.0f);
    __syncthreads();
    for (int i = tid; i < 3840; i += 1024) { int r = i / 60, c = i - r * 60; d2L[i] = B0[r * 61 + c]; }
}

// ---------------- Kernel B: per-item chain (64 items/block, 16 waves) ----------------
__global__ __launch_bounds__(1024) void chain_kernel(
    const float* __restrict__ spH, const float* __restrict__ spL,
    const float* __restrict__ dptH, const float* __restrict__ dptL,
    const float* __restrict__ d2H, const float* __restrict__ d2L,
    const float* __restrict__ w1_1, const float* __restrict__ b1_1,
    const float* __restrict__ w1_2, const float* __restrict__ b1_2,
    const float* __restrict__ w2_1, const float* __restrict__ b2_1,
    const float* __restrict__ w2_2, const float* __restrict__ b2_2,
    const float* __restrict__ wa1, const float* __restrict__ ba1,
    const float* __restrict__ wo1, const float* __restrict__ bo1,
    const float* __restrict__ wo2, const float* __restrict__ bo2,
    const int* __restrict__ mI,
    float* __restrict__ out, float* __restrict__ aH, float* __restrict__ aL)
{
    __shared__ float HA[64 * 65];
    __shared__ float HB[64 * 65];
    __shared__ float LA[64 * 65];
    __shared__ float LB[64 * 65];
    __shared__ float XLs[64];
    __shared__ float PH[16 * 64], PL[16 * 64];

    const int tid = threadIdx.x;
    const int w = __builtin_amdgcn_readfirstlane(tid >> 6);
    const int l = tid & 63;
    const int b0 = blockIdx.x * 64;
    const int b = b0 + l;
    const float mf = (float)(*mI);

    for (int i = tid; i < 4032; i += 1024) {
        int r = i / 63, c = i - r * 63;
        HA[r * 65 + c] = spH[(size_t)b0 * 63 + i];
    }
    if (tid < 64) XLs[tid] = spL[b0 + tid];
    __syncthreads();

    // s1: H 63->45 ; L 1->15
    dlayer<63, 63, 3>(w1_1, b1_1, HA + l * 65, HB + l * 65, 45, w * 3, 1.0f);
    dlayer<1, 1, 1>(w2_1, b2_1, XLs + l, LA + l * 65, 15, w, 1.0f);
    __syncthreads();
    // s2: H 45->30 ; L 15->30
    dlayer<45, 45, 2>(w1_2, b1_2, HB + l * 65, HA + l * 65, 30, w * 2, 1.0f);
    dlayer<15, 15, 2>(w2_2, b2_2, LA + l * 65, LB + l * 65, 30, w * 2, 1.0f);
    __syncthreads();
    // data_HSI / data_LiDAR copies + s3: 30->60 (wa1) both branches
    for (int i = tid; i < 1920; i += 1024) {
        int r = i / 30, c = i - r * 30;
        out[(size_t)b0 * 30 + i] = HA[r * 65 + c];
        out[OFF1 + (size_t)b0 * 30 + i] = LB[r * 65 + c];
    }
    dlayer<30, 30, 4>(wa1, ba1, HA + l * 65, HB + l * 65, 60, w * 4, 1.0f);
    dlayer<30, 30, 4>(wa1, ba1, LB + l * 65, LA + l * 65, 60, w * 4, 1.0f);
    __syncthreads();
    // s4: S = H1 @ D2^T  (60->64) both branches
    dlayer<60, 60, 4>(d2H, nullptr, HB + l * 65, HA + l * 65, 64, w * 4, 1.0f);
    dlayer<60, 60, 4>(d2L, nullptr, LA + l * 65, LB + l * 65, 64, w * 4, 1.0f);
    __syncthreads();
    // s5: exp(S - max) both branches
    softmax_exp4(HA + l * 65, HB + l * 65, PH, w, l);
    softmax_exp4(LB + l * 65, LA + l * 65, PL, w, l);
    __syncthreads();
    // A-matrix writes (only consumed when m != 1)
    if (mf != 1.0f) {
        for (int i = tid; i < 4096; i += 1024) {
            int r = i >> 6, j = i & 63;
            aH[(size_t)b0 * 64 + i] = HB[r * 65 + j] * inv16(PH, r);
            aL[(size_t)b0 * 64 + i] = LA[r * 65 + j] * inv16(PL, r);
        }
    }
    {
        const float invH = inv16(PH, l);
        const float invL = inv16(PL, l);
        dlayerT<64, 30, 2>(dptH, HB + l * 65, HA + l * 65, 30, w * 2, invH);
        dlayerT<64, 30, 2>(dptL, LA + l * 65, LB + l * 65, 30, w * 2, invL);
    }
    __syncthreads();
    // s8: 30->60 (wa1) both branches
    dlayer<30, 30, 4>(wa1, ba1, HA + l * 65, HB + l * 65, 60, w * 4, 1.0f);
    dlayer<30, 30, 4>(wa1, ba1, LB + l * 65, LA + l * 65, 60, w * 4, 1.0f);
    __syncthreads();
    // HSI_A / LiDAR_A copies
    for (int i = tid; i < 3840; i += 1024) {
        int r = i / 60, c = i - r * 60;
        out[OFF2 + (size_t)b0 * 60 + i] = HB[r * 65 + c];
        out[OFF4 + (size_t)b0 * 60 + i] = LA[r * 65 + c];
    }
    // o1: 120->60 = wo1[:, :60]@A60l + wo1[:, 60:]@A60h, chunked
    {
        const int o0 = w * 4;
        float acc[4];
#pragma unroll
        for (int k = 0; k < 4; ++k) acc[k] = (o0 + k < 60) ? bo1[o0 + k] : 0.0f;
#pragma unroll
        for (int c0 = 0; c0 < 60; c0 += 15) {
            float x[15];
#pragma unroll
            for (int j = 0; j < 15; ++j) x[j] = LA[l * 65 + c0 + j];
#pragma unroll
            for (int k = 0; k < 4; ++k) {
                int oc = o0 + k; oc = oc < 60 ? oc : 59;
                const float* Wr = wo1 + oc * 120 + c0;
                float a = acc[k];
#pragma unroll
                for (int j = 0; j < 15; ++j) a = fmaf(Wr[j], x[j], a);
                acc[k] = a;
            }
        }
#pragma unroll
        for (int c0 = 0; c0 < 60; c0 += 15) {
            float x[15];
#pragma unroll
            for (int j = 0; j < 15; ++j) x[j] = HB[l * 65 + c0 + j];
#pragma unroll
            for (int k = 0; k < 4; ++k) {
                int oc = o0 + k; oc = oc < 60 ? oc : 59;
                const float* Wr = wo1 + oc * 120 + 60 + c0;
                float a = acc[k];
#pragma unroll
                for (int j = 0; j < 15; ++j) a = fmaf(Wr[j], x[j], a);
                acc[k] = a;
            }
        }
#pragma unroll
        for (int k = 0; k < 4; ++k) {
            int o = o0 + k;
            if (o < 60) HA[l * 65 + o] = acc[k];
        }
    }
    __syncthreads();
    // o2: 60->7 (waves 0-6, one output each)
    if (w < 7) {
        float a = bo2[w];
        const float* Wr = wo2 + w * 60;
#pragma unroll
        for (int c0 = 0; c0 < 60; c0 += 15) {
            float x[15];
#pragma unroll
            for (int j = 0; j < 15; ++j) x[j] = HA[l * 65 + c0 + j];
#pragma unroll
            for (int j = 0; j < 15; ++j) a = fmaf(Wr[c0 + j], x[j], a);
        }
        out[OFF6 + (size_t)b * 7 + w] = a;
    }
}

// ---------------- Kernel D1: momentum partial (only real work when m != 1) ----------------
__global__ __launch_bounds__(256) void momentum_partial_kernel(
    const float* __restrict__ dataH, const float* __restrict__ dataL,
    const float* __restrict__ aH, const float* __restrict__ aL,
    float* __restrict__ pH, float* __restrict__ pL,
    const int* __restrict__ mI)
{
    const float mf = (float)(*mI);
    if (mf == 1.0f) return;  // P is never read when m == 1
    const int tid = threadIdx.x;
    const int chunk = blockIdx.x & 63;
    const int mod = blockIdx.x >> 6;
    const float* data = mod ? dataL : dataH;
    const float* A = mod ? aL : aH;
    float* P = mod ? pL : pH;
    const int b0 = chunk * 256;
    const int j = tid & 63;
    const int g = tid >> 6;
    float acc[8];
#pragma unroll
    for (int k = 0; k < 8; ++k) acc[k] = 0.f;
    for (int bb = 0; bb < 256; ++bb) {
        float a = A[(size_t)(b0 + bb) * 64 + j];
#pragma unroll
        for (int k = 0; k < 8; ++k) {
            int c = g + 4 * k; c = c < 30 ? c : 29;
            acc[k] = fmaf(data[(size_t)(b0 + bb) * 30 + c], a, acc[k]);
        }
    }
#pragma unroll
    for (int k = 0; k < 8; ++k) {
        int c = g + 4 * k;
        if (c < 30) P[chunk * 1920 + c * 64 + j] = acc[k];
    }
}

// ---------------- Kernel D2: Dn = m*Dp + (1-m)*sum(partials) ----------------
__global__ __launch_bounds__(256) void momentum_final_kernel(
    const float* __restrict__ dptH, const float* __restrict__ dptL,
    const float* __restrict__ pH, const float* __restrict__ pL,
    const int* __restrict__ mI, float* __restrict__ out)
{
    int t = blockIdx.x * 256 + threadIdx.x;
    if (t >= 3840) return;
    const int mod = t >= 1920;
    const int idx = mod ? t - 1920 : t;
    const int c = idx >> 6, j = idx & 63;
    const float mf = (float)(*mI);
    const float* dpt = mod ? dptL : dptH;
    float v = mf * dpt[j * 30 + c];
    if (mf != 1.0f) {
        const float* P = mod ? pL : pH;
        float s = 0.f;
        for (int k = 0; k < 64; ++k) s += P[k * 1920 + idx];
        v += (1.0f - mf) * s;
    }
    out[(mod ? OFF5 : OFF3) + idx] = v;
}

extern "C" void kernel_launch(void* const* d_in, const int* in_sizes, int n_in,
                              void* d_out, int out_size, void* d_ws, size_t ws_size,
                              hipStream_t stream) {
    const float* H_HSI        = (const float*)d_in[0];
    const float* H_LiDAR      = (const float*)d_in[1];
    const float* HSI_D        = (const float*)d_in[2];
    const float* LiDAR_D      = (const float*)d_in[3];
    const float* Patch_HSI    = (const float*)d_in[4];
    const float* Patch_LiDAR  = (const float*)d_in[5];
    const float* D_Patch_HSI  = (const float*)d_in[6];
    const float* D_Patch_LiDAR= (const float*)d_in[7];
    const int*   mI           = (const int*)d_in[9];
    const float* w1_1 = (const float*)d_in[12];
    const float* b1_1 = (const float*)d_in[13];
    const float* w1_2 = (const float*)d_in[14];
    const float* b1_2 = (const float*)d_in[15];
    const float* w2_1 = (const float*)d_in[16];
    const float* b2_1 = (const float*)d_in[17];
    const float* w2_2 = (const float*)d_in[18];
    const float* b2_2 = (const float*)d_in[19];
    const float* wa1  = (const float*)d_in[20];
    const float* ba1  = (const float*)d_in[21];
    const float* wa2  = (const float*)d_in[22];
    const float* ba2  = (const float*)d_in[23];
    const float* wo1  = (const float*)d_in[24];
    const float* bo1  = (const float*)d_in[25];
    const float* wo2  = (const float*)d_in[26];
    const float* bo2  = (const float*)d_in[27];

    float* out = (float*)d_out;
    float* ws  = (float*)d_ws;

    patch_attend_kernel<<<NB / 4, 256, 0, stream>>>(
        Patch_HSI, H_HSI, Patch_LiDAR, H_LiDAR, ws + SPH_OFF, ws + SPL_OFF);
    patch_attend_kernel<<<DN / 4, 256, 0, stream>>>(
        D_Patch_HSI, HSI_D, D_Patch_LiDAR, LiDAR_D, ws + DSPH_OFF, ws + DSPL_OFF);
    dict_chain_kernel<<<1, 1024, 0, stream>>>(
        ws + DSPH_OFF, ws + DSPL_OFF,
        w1_1, b1_1, w1_2, b1_2, w2_1, b2_1, w2_2, b2_2, wa2, ba2,
        ws + DPTH_OFF, ws + DPTL_OFF, ws + D2H_OFF, ws + D2L_OFF);
    chain_kernel<<<NB / 64, 1024, 0, stream>>>(
        ws + SPH_OFF, ws + SPL_OFF,
        ws + DPTH_OFF, ws + DPTL_OFF, ws + D2H_OFF, ws + D2L_OFF,
        w1_1, b1_1, w1_2, b1_2, w2_1, b2_1, w2_2, b2_2,
        wa1, ba1, wo1, bo1, wo2, bo2, mI,
        out, ws + AH_OFF, ws + AL_OFF);
    momentum_partial_kernel<<<128, 256, 0, stream>>>(
        out, out + OFF1, ws + AH_OFF, ws + AL_OFF, ws + PH_OFF, ws + PL_OFF, mI);
    momentum_final_kernel<<<15, 256, 0, stream>>>(
        ws + DPTH_OFF, ws + DPTL_OFF, ws + PH_OFF, ws + PL_OFF, mI, out);
}